// Round 5
// baseline (523.965 us; speedup 1.0000x reference)
//
#include <hip/hip_runtime.h>
#include <hip/hip_bf16.h>

// Problem dims (fixed by reference):
//   x:  [B=16, c_in=64, T=64, N=512] fp32
//   La: [B=16, N=512, N=512] fp32
//   W:  [c_out=64, K*c_in=192] fp32
//   out:[B, 64, T, N] fp32
// v5 restructure (W commutes with La over different axes):
//   out = y0 + y1@La^T + y2@La2^T,  La2 = La@La
//   y0 = (W0-W2)@x ; y1 = W1@x ; y2 = 2*W2@x   (channel mix, K=64)
// This deletes proj (K=192 GEMM) and the standalone x cvt entirely.
// (v5 resubmit: round-4 bench died in container acquisition, not the kernel;
//  source re-audited for OOB/deadlock, no defect found.)

#define B_   16
#define CIN  64
#define T_   64
#define N_   512
#define M_   4096   // 64 o * 64 t rows per batch (= CIN*T_ before)
#define KDIM 512
#define COUT 64
#define LQ   32768  // T_*N_

typedef __bf16 bf16x8 __attribute__((ext_vector_type(8)));
typedef float  floatx4 __attribute__((ext_vector_type(4)));

__device__ __forceinline__ float bf2f(unsigned short u) {
    unsigned int v = ((unsigned int)u) << 16;
    return __builtin_bit_cast(float, v);
}
__device__ __forceinline__ unsigned short f2bf(float f) {
    unsigned int u = __builtin_bit_cast(unsigned int, f);
    unsigned int lsb = (u >> 16) & 1u;
    u += 0x7fffu + lsb;           // round-to-nearest-even
    return (unsigned short)(u >> 16);
}

// async global->LDS, 16B per lane; LDS dest = wave-uniform base + lane*16
#define GLOAD_LDS16(gp, lp)                                                  \
    __builtin_amdgcn_global_load_lds(                                        \
        (const __attribute__((address_space(1))) void*)(gp),                 \
        (__attribute__((address_space(3))) void*)(lp), 16, 0, 0)

// ---- K0a: pack W into 3 channel-mix matrices, A-operand layout [o][c] ----
// Wp rows 0-63: W0-W2 ; 64-127: W1 ; 128-191: 2*W2
__global__ __launch_bounds__(256) void pack_w3(
    const float* __restrict__ W, unsigned short* __restrict__ Wp)
{
    int idx = blockIdx.x * 256 + threadIdx.x;   // 192*64
    if (idx < 192 * 64) {
        int op = idx >> 6, c = idx & 63;
        int i = op >> 6, o = op & 63;
        float v;
        if (i == 0)      v = W[o * 192 + c * 3 + 0] - W[o * 192 + c * 3 + 2];
        else if (i == 1) v = W[o * 192 + c * 3 + 1];
        else             v = 2.0f * W[o * 192 + c * 3 + 2];
        Wp[idx] = f2bf(v);
    }
}

// ---- K0b: La fp32 -> bf16 row-major AND bf16 transposed, one pass ----
__global__ __launch_bounds__(256) void cvt_la_dual(
    const float* __restrict__ La,
    unsigned short* __restrict__ Lab,
    unsigned short* __restrict__ LaT)
{
    __shared__ unsigned short t64[64][68];
    int b  = blockIdx.z;
    int r0 = blockIdx.y * 64;
    int c0 = blockIdx.x * 64;
    int t   = threadIdx.x;
    int row = t >> 2;
    int cg  = (t & 3) * 16;

    const float* src = La + (size_t)b * N_ * N_ + (size_t)(r0 + row) * N_ + c0 + cg;
    unsigned short s[16];
#pragma unroll
    for (int u = 0; u < 4; u++) {
        float4 f = *(const float4*)(src + u * 4);
        s[u * 4 + 0] = f2bf(f.x); s[u * 4 + 1] = f2bf(f.y);
        s[u * 4 + 2] = f2bf(f.z); s[u * 4 + 3] = f2bf(f.w);
    }
    union { unsigned short h[8]; uint4 u; } p0, p1;
#pragma unroll
    for (int u = 0; u < 8; u++) { p0.h[u] = s[u]; p1.h[u] = s[8 + u]; }
    unsigned short* d0 = Lab + (size_t)b * N_ * N_ + (size_t)(r0 + row) * N_ + c0 + cg;
    *(uint4*)d0 = p0.u;
    *(uint4*)(d0 + 8) = p1.u;
#pragma unroll
    for (int u = 0; u < 16; u++) t64[row][cg + u] = s[u];
    __syncthreads();
    int col = t >> 2;
    int rg  = (t & 3) * 16;
    union { unsigned short h[8]; uint4 u; } q0, q1;
#pragma unroll
    for (int u = 0; u < 8; u++) { q0.h[u] = t64[rg + u][col]; q1.h[u] = t64[rg + 8 + u][col]; }
    unsigned short* d1 = LaT + (size_t)b * N_ * N_ + (size_t)(c0 + col) * N_ + r0 + rg;
    *(uint4*)d1 = q0.u;
    *(uint4*)(d1 + 8) = q1.u;
}

#define BM 128
#define BN 128
#define BK 32
#define KIT  (KDIM / BK)
#define SBUF (BM * BK)

// ---- K1: La2[q][n] = sum_p La[q,p] * LaT[n,p]  (proven round-3 kernel) ----
__global__ __launch_bounds__(256) void gemm_la2(
    const unsigned short* __restrict__ A,
    const unsigned short* __restrict__ Bm,
    unsigned short* __restrict__ C)
{
    int h     = blockIdx.x;
    int g     = h & 7;
    int idx   = h >> 3;
    int batch = g * 2 + (idx >> 4);
    int local = idx & 15;
    int n0    = (local & 3) * BN;
    int m0    = (local >> 2) * BM;

    A  += (size_t)batch * N_ * KDIM;
    Bm += (size_t)batch * N_ * KDIM;
    C  += (size_t)batch * N_ * N_;

    __shared__ __align__(16) unsigned short As[3 * SBUF];
    __shared__ __align__(16) unsigned short Bs[3 * SBUF];

    int tid  = threadIdx.x;
    int lane = tid & 63;
    int wave = tid >> 6;
    int wm   = (wave >> 1) * 64;
    int wn   = (wave & 1) * 64;
    int l15  = lane & 15;
    int quad = lane >> 4;

    int r16 = lane >> 2;
    int sch = lane & 3;
    int gch = sch ^ ((r16 >> 1) & 3);

    const unsigned short* gA0 = A  + (size_t)(m0 + wave * 16 + r16) * KDIM + gch * 8;
    const unsigned short* gA1 = gA0 + (size_t)64 * KDIM;
    const unsigned short* gB0 = Bm + (size_t)(n0 + wave * 16 + r16) * KDIM + gch * 8;
    const unsigned short* gB1 = gB0 + (size_t)64 * KDIM;

    int dA0 = (wave * 16) * BK;
    int dA1 = (64 + wave * 16) * BK;

#define STAGE2(kk, bo) do {                                       \
        GLOAD_LDS16(gA0 + (kk) * BK, &As[(bo) + dA0]);            \
        GLOAD_LDS16(gA1 + (kk) * BK, &As[(bo) + dA1]);            \
        GLOAD_LDS16(gB0 + (kk) * BK, &Bs[(bo) + dA0]);            \
        GLOAD_LDS16(gB1 + (kk) * BK, &Bs[(bo) + dA1]);            \
    } while (0)

    int aoff[4], boff[4];
    int sl = quad ^ ((l15 >> 1) & 3);
#pragma unroll
    for (int im = 0; im < 4; im++) aoff[im] = (wm + im * 16 + l15) * BK + sl * 8;
#pragma unroll
    for (int jn = 0; jn < 4; jn++) boff[jn] = (wn + jn * 16 + l15) * BK + sl * 8;

    floatx4 acc[4][4];
#pragma unroll
    for (int i = 0; i < 4; i++)
#pragma unroll
        for (int j = 0; j < 4; j++) acc[i][j] = (floatx4)0.0f;

    STAGE2(0, 0);
    STAGE2(1, SBUF);

#pragma unroll
    for (int k = 0; k < KIT; ++k) {
        if (k < KIT - 1) asm volatile("s_waitcnt vmcnt(4)" ::: "memory");
        else             asm volatile("s_waitcnt vmcnt(0)" ::: "memory");
        __builtin_amdgcn_s_barrier();
        if (k + 2 < KIT) STAGE2(k + 2, ((k + 2) % 3) * SBUF);

        const int cb = (k % 3) * SBUF;
        bf16x8 af[4], bf[4];
#pragma unroll
        for (int im = 0; im < 4; im++)
            af[im] = __builtin_bit_cast(bf16x8, *(const uint4*)&As[cb + aoff[im]]);
#pragma unroll
        for (int jn = 0; jn < 4; jn++)
            bf[jn] = __builtin_bit_cast(bf16x8, *(const uint4*)&Bs[cb + boff[jn]]);
#pragma unroll
        for (int im = 0; im < 4; im++)
#pragma unroll
            for (int jn = 0; jn < 4; jn++)
                acc[im][jn] = __builtin_amdgcn_mfma_f32_16x16x32_bf16(
                    af[im], bf[jn], acc[im][jn], 0, 0, 0);
    }
#undef STAGE2

#pragma unroll
    for (int im = 0; im < 4; im++)
#pragma unroll
        for (int jn = 0; jn < 4; jn++) {
            int c = n0 + wn + jn * 16 + l15;
#pragma unroll
            for (int r = 0; r < 4; r++) {
                int m = m0 + wm + im * 16 + quad * 4 + r;
                C[(size_t)m * N_ + c] = f2bf(acc[im][jn][r]);
            }
        }
}

// ---- K2: chanmix — y_i[b][o][l] = sum_c Wp_i[o][c] * x[b][c][l], K=64 ----
// Stages x^T [128 l][64 c] in LDS with chunk swizzle p=(s+2l)&7 (conflict-
// free write AND read). W frags register-resident. Direct bf16 stores.
__global__ __launch_bounds__(256) void chanmix(
    const float* __restrict__ x,
    const unsigned short* __restrict__ Wp,
    unsigned short* __restrict__ y0,
    unsigned short* __restrict__ y1,
    unsigned short* __restrict__ y2)
{
    __shared__ __align__(16) unsigned short Xs[128 * 72];   // 18 KB

    int b  = blockIdx.y;
    int l0 = blockIdx.x * 128;
    int tid  = threadIdx.x;
    int lane = tid & 63;
    int wave = tid >> 6;
    int l15  = lane & 15;
    int quad = lane >> 4;

    // W fragments: wave covers o'-rows [wave*48, wave*48+48) = 3 tiles of 16
    bf16x8 wf[3][2];
#pragma unroll
    for (int t3 = 0; t3 < 3; t3++)
#pragma unroll
        for (int ks = 0; ks < 2; ks++)
            wf[t3][ks] = __builtin_bit_cast(bf16x8, *(const uint4*)(
                Wp + (size_t)(wave * 48 + t3 * 16 + l15) * 64 + ks * 32 + quad * 8));

    // stage x^T: thread owns channel cth, l-window lgrp*32..+32 (128B contig)
    int cth  = tid & 63;
    int lgrp = tid >> 6;
    const float* xrow = x + ((size_t)b * CIN + cth) * LQ + l0 + lgrp * 32;
#pragma unroll
    for (int u = 0; u < 8; u++) {
        float4 f = *(const float4*)(xrow + u * 4);
        float fv[4] = { f.x, f.y, f.z, f.w };
#pragma unroll
        for (int j = 0; j < 4; j++) {
            int ll = lgrp * 32 + u * 4 + j;
            int p  = ((cth >> 3) + 2 * ll) & 7;
            Xs[ll * 72 + p * 8 + (cth & 7)] = f2bf(fv[j]);
        }
    }
    __syncthreads();

    floatx4 acc[3][8];
#pragma unroll
    for (int i = 0; i < 3; i++)
#pragma unroll
        for (int j = 0; j < 8; j++) acc[i][j] = (floatx4)0.0f;

#pragma unroll
    for (int lf = 0; lf < 8; lf++) {
        int lrow = lf * 16 + l15;
#pragma unroll
        for (int ks = 0; ks < 2; ks++) {
            int p = ((ks * 4 + quad) + 2 * lrow) & 7;
            bf16x8 bfr = __builtin_bit_cast(bf16x8,
                *(const uint4*)&Xs[lrow * 72 + p * 8]);
            acc[0][lf] = __builtin_amdgcn_mfma_f32_16x16x32_bf16(wf[0][ks], bfr, acc[0][lf], 0, 0, 0);
            acc[1][lf] = __builtin_amdgcn_mfma_f32_16x16x32_bf16(wf[1][ks], bfr, acc[1][lf], 0, 0, 0);
            acc[2][lf] = __builtin_amdgcn_mfma_f32_16x16x32_bf16(wf[2][ks], bfr, acc[2][lf], 0, 0, 0);
        }
    }

    // direct stores: frag col(l15)=l, row(quad*4+r)=o'
#pragma unroll
    for (int t3 = 0; t3 < 3; t3++) {
        int opb = wave * 48 + t3 * 16;                 // multiple of 16
        unsigned short* yp = (opb < 64) ? y0 : ((opb < 128) ? y1 : y2);
        int o = opb & 63;
        unsigned short* dst = yp + ((size_t)b * 64 + o + quad * 4) * LQ + l0 + l15;
#pragma unroll
        for (int lf = 0; lf < 8; lf++)
#pragma unroll
            for (int r = 0; r < 4; r++)
                dst[(size_t)r * LQ + lf * 16] = f2bf(acc[t3][lf][r]);
    }
}

// ---- K3: gemm_out — out[m=(o,t)][q] = y0 + sum_p y1[m][p]La[q][p]
//                                           + sum_p y2[m][p]La2[q][p] ----
// Two A-streams + two B-streams, 2-buffer / 2-barrier / counted vmcnt(8).
__global__ __launch_bounds__(256) void gemm_out(
    const unsigned short* __restrict__ A1,
    const unsigned short* __restrict__ A2,
    const unsigned short* __restrict__ B1,
    const unsigned short* __restrict__ B2,
    const unsigned short* __restrict__ Y0,
    float* __restrict__ out)
{
    int h     = blockIdx.x;
    int g     = h & 7;
    int idx   = h >> 3;                 // 0..255
    int batch = g * 2 + (idx >> 7);
    int local = idx & 127;
    int n0    = (local & 3) * BN;
    int m0    = (local >> 2) * BM;

    A1 += (size_t)batch * M_ * KDIM;
    A2 += (size_t)batch * M_ * KDIM;
    B1 += (size_t)batch * N_ * KDIM;
    B2 += (size_t)batch * N_ * KDIM;
    Y0 += (size_t)batch * M_ * N_;
    out += (size_t)batch * M_ * N_;

    __shared__ __align__(16) unsigned short As1[2 * SBUF];   // 16 KB each
    __shared__ __align__(16) unsigned short As2[2 * SBUF];
    __shared__ __align__(16) unsigned short Bs1[2 * SBUF];
    __shared__ __align__(16) unsigned short Bs2[2 * SBUF];

    int tid  = threadIdx.x;
    int lane = tid & 63;
    int wave = tid >> 6;
    int wm   = (wave >> 1) * 64;
    int wn   = (wave & 1) * 64;
    int l15  = lane & 15;
    int quad = lane >> 4;

    int r16 = lane >> 2;
    int sch = lane & 3;
    int gch = sch ^ ((r16 >> 1) & 3);

    const unsigned short* gA10 = A1 + (size_t)(m0 + wave * 16 + r16) * KDIM + gch * 8;
    const unsigned short* gA11 = gA10 + (size_t)64 * KDIM;
    const unsigned short* gA20 = A2 + (size_t)(m0 + wave * 16 + r16) * KDIM + gch * 8;
    const unsigned short* gA21 = gA20 + (size_t)64 * KDIM;
    const unsigned short* gB10 = B1 + (size_t)(n0 + wave * 16 + r16) * KDIM + gch * 8;
    const unsigned short* gB11 = gB10 + (size_t)64 * KDIM;
    const unsigned short* gB20 = B2 + (size_t)(n0 + wave * 16 + r16) * KDIM + gch * 8;
    const unsigned short* gB21 = gB20 + (size_t)64 * KDIM;

    int d0 = (wave * 16) * BK;
    int d1 = (64 + wave * 16) * BK;

#define STAGE8(kk, bo) do {                                        \
        GLOAD_LDS16(gA10 + (kk) * BK, &As1[(bo) + d0]);            \
        GLOAD_LDS16(gA11 + (kk) * BK, &As1[(bo) + d1]);            \
        GLOAD_LDS16(gA20 + (kk) * BK, &As2[(bo) + d0]);            \
        GLOAD_LDS16(gA21 + (kk) * BK, &As2[(bo) + d1]);            \
        GLOAD_LDS16(gB10 + (kk) * BK, &Bs1[(bo) + d0]);            \
        GLOAD_LDS16(gB11 + (kk) * BK, &Bs1[(bo) + d1]);            \
        GLOAD_LDS16(gB20 + (kk) * BK, &Bs2[(bo) + d0]);            \
        GLOAD_LDS16(gB21 + (kk) * BK, &Bs2[(bo) + d1]);            \
    } while (0)

    int aoff[4], boff[4];
    int sl = quad ^ ((l15 >> 1) & 3);
#pragma unroll
    for (int im = 0; im < 4; im++) aoff[im] = (wm + im * 16 + l15) * BK + sl * 8;
#pragma unroll
    for (int jn = 0; jn < 4; jn++) boff[jn] = (wn + jn * 16 + l15) * BK + sl * 8;

    floatx4 acc1[4][4], acc2[4][4];
#pragma unroll
    for (int i = 0; i < 4; i++)
#pragma unroll
        for (int j = 0; j < 4; j++) { acc1[i][j] = (floatx4)0.0f; acc2[i][j] = (floatx4)0.0f; }

    STAGE8(0, 0);

#pragma unroll
    for (int k = 0; k < KIT; ++k) {
        // barrier #1: every wave finished computing tile k-1 -> its buffer
        // (which tile k+1 will overwrite) is free.
        __builtin_amdgcn_s_barrier();
        if (k + 1 < KIT) STAGE8(k + 1, ((k + 1) & 1) * SBUF);
        // wait tile k's 8 loads (oldest); keep tile k+1's 8 in flight.
        if (k + 1 < KIT) asm volatile("s_waitcnt vmcnt(8)" ::: "memory");
        else             asm volatile("s_waitcnt vmcnt(0)" ::: "memory");
        __builtin_amdgcn_s_barrier();   // all waves' loads for tile k done

        const int cb = (k & 1) * SBUF;
        bf16x8 a1[4], a2[4], b1[4], b2[4];
#pragma unroll
        for (int im = 0; im < 4; im++) {
            a1[im] = __builtin_bit_cast(bf16x8, *(const uint4*)&As1[cb + aoff[im]]);
            a2[im] = __builtin_bit_cast(bf16x8, *(const uint4*)&As2[cb + aoff[im]]);
        }
#pragma unroll
        for (int jn = 0; jn < 4; jn++) {
            b1[jn] = __builtin_bit_cast(bf16x8, *(const uint4*)&Bs1[cb + boff[jn]]);
            b2[jn] = __builtin_bit_cast(bf16x8, *(const uint4*)&Bs2[cb + boff[jn]]);
        }
#pragma unroll
        for (int im = 0; im < 4; im++)
#pragma unroll
            for (int jn = 0; jn < 4; jn++) {
                acc1[im][jn] = __builtin_amdgcn_mfma_f32_16x16x32_bf16(
                    a1[im], b1[jn], acc1[im][jn], 0, 0, 0);
                acc2[im][jn] = __builtin_amdgcn_mfma_f32_16x16x32_bf16(
                    a2[im], b2[jn], acc2[im][jn], 0, 0, 0);
            }
    }
#undef STAGE8

    // epilogue: out = acc1 + acc2 + y0   (C/D: col=l15, row=quad*4+r)
#pragma unroll
    for (int im = 0; im < 4; im++)
#pragma unroll
        for (int jn = 0; jn < 4; jn++) {
            int c = n0 + wn + jn * 16 + l15;
#pragma unroll
            for (int r = 0; r < 4; r++) {
                int m = m0 + wm + im * 16 + quad * 4 + r;
                size_t idx2 = (size_t)m * N_ + c;
                out[idx2] = acc1[im][jn][r] + acc2[im][jn][r] + bf2f(Y0[idx2]);
            }
        }
}

extern "C" void kernel_launch(void* const* d_in, const int* in_sizes, int n_in,
                              void* d_out, int out_size, void* d_ws, size_t ws_size,
                              hipStream_t stream) {
    const float* x  = (const float*)d_in[0];
    const float* La = (const float*)d_in[1];
    const float* W  = (const float*)d_in[2];
    float* out = (float*)d_out;

    const size_t n_x  = (size_t)B_ * CIN * T_ * N_;   // 33,554,432
    const size_t n_La = (size_t)B_ * N_ * N_;         //  4,194,304

    char* ws = (char*)d_ws;
    unsigned short* y0b  = (unsigned short*)ws;                         // 64 MiB
    unsigned short* y1b  = (unsigned short*)(ws + n_x * 2);             // 64 MiB
    unsigned short* y2b  = (unsigned short*)(ws + n_x * 4);             // 64 MiB
    unsigned short* Lab  = (unsigned short*)(ws + n_x * 6);             //  8 MiB
    unsigned short* LaT  = (unsigned short*)(ws + n_x * 6 + n_La * 2);  //  8 MiB
    unsigned short* La2b = (unsigned short*)(ws + n_x * 6 + n_La * 4);  //  8 MiB
    unsigned short* Wp   = (unsigned short*)(ws + n_x * 6 + n_La * 6);  // 24 KiB

    pack_w3<<<48, 256, 0, stream>>>(W, Wp);
    cvt_la_dual<<<dim3(8, 8, 16), 256, 0, stream>>>(La, Lab, LaT);
    gemm_la2<<<256, 256, 0, stream>>>(Lab, LaT, La2b);

    // channel mix: y0,y1,y2 from fp32 x (also does the bf16 cvt)
    chanmix<<<dim3(LQ / 128, B_), 256, 0, stream>>>(x, Wp, y0b, y1b, y2b);

    // node GEMM: out = y0 + y1@La^T + y2@La2^T  (fp32 out, direct)
    gemm_out<<<2048, 256, 0, stream>>>(y1b, y2b, Lab, La2b, y0b, out);
}